// Round 7
// baseline (582.584 us; speedup 1.0000x reference)
//
#include <hip/hip_runtime.h>
#include <stdint.h>

#define BSZ  4
#define NSEQ 2048
#define DM   128
#define NH   8
#define DK   16
#define LOG2E 1.4426950408889634f
// LOG2E / sqrt(128): folded into Wq/bq so scores exit QK^T in log2 domain
#define SCALE_QL 0.1275156338341935f
// mask weight: w = mask * 2^-18 (exact in bf16); folded into V' and the
// l-reduction A-operand. p = exp2(S) stays <= ~2^10, l ~ 1e-2 -> safe fp32.
#define W_SCALE 3.814697265625e-6f

typedef __bf16          bf16x8v __attribute__((ext_vector_type(8)));
typedef float           f32x2   __attribute__((ext_vector_type(2)));
typedef float           f32x4   __attribute__((ext_vector_type(4)));
typedef float           f32x16  __attribute__((ext_vector_type(16)));
typedef unsigned short  u16x8   __attribute__((ext_vector_type(8)));
typedef unsigned short  u16x4   __attribute__((ext_vector_type(4)));
typedef unsigned int    u32x2   __attribute__((ext_vector_type(2)));
typedef unsigned int    u32x4   __attribute__((ext_vector_type(4)));

__device__ __forceinline__ unsigned short f2bf(float f) {
    unsigned u = __float_as_uint(f);
    u = (u + 0x7fffu + ((u >> 16) & 1u)) >> 16;
    return (unsigned short)u;
}

__device__ __forceinline__ unsigned int pack2bf(float a, float b) {
#if __has_builtin(__builtin_amdgcn_cvt_pk_bf16_f32)
    typedef __bf16 bf16x2 __attribute__((ext_vector_type(2)));
    bf16x2 v = __builtin_amdgcn_cvt_pk_bf16_f32(a, b);
    return __builtin_bit_cast(unsigned int, v);
#else
    return (unsigned)f2bf(a) | ((unsigned)f2bf(b) << 16);
#endif
}

__device__ __forceinline__ float exp2_(float x) {
#if __has_builtin(__builtin_amdgcn_exp2f)
    return __builtin_amdgcn_exp2f(x);
#else
    return exp2f(x);
#endif
}

// load 8 consecutive f32, scale, convert -> u16x8 bf16 fragment
__device__ __forceinline__ u16x8 cvt8(const float* p, float sc) {
    const f32x4 a = *reinterpret_cast<const f32x4*>(p);
    const f32x4 b = *reinterpret_cast<const f32x4*>(p + 4);
    u32x4 u = {pack2bf(a[0] * sc, a[1] * sc), pack2bf(a[2] * sc, a[3] * sc),
               pack2bf(b[0] * sc, b[1] * sc), pack2bf(b[2] * sc, b[3] * sc)};
    return __builtin_bit_cast(u16x8, u);
}

__device__ __forceinline__ f32x4 mfma16(u16x8 a, u16x8 b, f32x4 c) {
    return __builtin_amdgcn_mfma_f32_16x16x32_bf16(
        __builtin_bit_cast(bf16x8v, a), __builtin_bit_cast(bf16x8v, b), c, 0, 0, 0);
}
__device__ __forceinline__ f32x16 mfma32(u16x8 a, u16x8 b, f32x16 c) {
    return __builtin_amdgcn_mfma_f32_32x32x16_bf16(
        __builtin_bit_cast(bf16x8v, a), __builtin_bit_cast(bf16x8v, b), c, 0, 0, 0);
}

// software grid barrier: safe because grid=1024 blocks with
// __launch_bounds__(256,4) guarantees 4 blocks/CU x 256 CU co-residency
// (LDS 17.4KB <= 40KB, VGPR <= 128). __threadfence = agent-scope fence
// (L2 writeback) for cross-XCD visibility per G16.
__device__ __forceinline__ void grid_barrier(unsigned* cnt, unsigned target) {
    __threadfence();
    __syncthreads();
    if (threadIdx.x == 0) {
        __hip_atomic_fetch_add(cnt, 1u, __ATOMIC_RELEASE, __HIP_MEMORY_SCOPE_AGENT);
        while (__hip_atomic_load(cnt, __ATOMIC_ACQUIRE, __HIP_MEMORY_SCOPE_AGENT) <
               target) {
            __builtin_amdgcn_s_sleep(1);
        }
    }
    __syncthreads();
}

// ---------------------------------------------------------------------------
// Fused qkv -> attn -> fc, single dispatch, 1024 blocks x 256 threads.
// ---------------------------------------------------------------------------
__global__ __launch_bounds__(256, 4) void k_fused(
    const float* __restrict__ x,
    const float* __restrict__ Wq, const float* __restrict__ bq,
    const float* __restrict__ Wk, const float* __restrict__ bk,
    const float* __restrict__ Wv, const float* __restrict__ bv,
    const float* __restrict__ Wfc, const float* __restrict__ bfc,
    const float* __restrict__ mask,
    float* __restrict__ out,
    unsigned short* __restrict__ Q, unsigned short* __restrict__ Kb,
    unsigned short* __restrict__ Vt, unsigned short* __restrict__ AO,
    unsigned short* __restrict__ WfcB, unsigned short* __restrict__ wb,
    unsigned* __restrict__ cnt)
{
    __shared__ __align__(16) char smem[17408];
    const int tid  = threadIdx.x;
    const int bid  = blockIdx.x;
    const int lane = tid & 63;
    const int wv   = tid >> 6;
    const int c    = lane & 15;
    const int quad = lane >> 4;
    const int hi   = lane >> 5;
    const int q32  = lane & 31;

    // ======================= phase 1: QKV projection ========================
    // block = (b, ntile16, t-half): stage x[b][:][16n] once, 3 mat-waves
    // each compute 4 d'-tiles; wave 3 converts Wfc + builds wb.
    {
        const int b   = bid >> 8;
        const int nt  = (bid >> 1) & 127;
        const int tp  = bid & 1;
        const int n0  = nt << 4;
        float* xs = reinterpret_cast<float*>(smem);   // [128][18] f32 (stride 18)

        // stage x: 128 rows x 16 f32, f32x2 chunks, coalesced-ish
        for (int k = tid; k < 1024; k += 256) {
            const int d = k >> 3, p = (k & 7) << 1;
            *reinterpret_cast<f32x2*>(&xs[d * 18 + p]) =
                *reinterpret_cast<const f32x2*>(
                    x + (size_t)(b * DM + d) * NSEQ + n0 + p);
        }
        __syncthreads();

        if (wv < 3) {
            // B-frag gather from LDS: B[k=d][n=c]; stride 18 -> 2-way only
            u16x8 xf[4];
#pragma unroll
            for (int kk = 0; kk < 4; ++kk) {
                float f[8];
#pragma unroll
                for (int j = 0; j < 8; ++j)
                    f[j] = xs[(kk * 32 + quad * 8 + j) * 18 + c];
                u32x4 u = {pack2bf(f[0], f[1]), pack2bf(f[2], f[3]),
                           pack2bf(f[4], f[5]), pack2bf(f[6], f[7])};
                xf[kk] = __builtin_bit_cast(u16x8, u);
            }

            const float* W    = (wv == 0) ? Wq : (wv == 1) ? Wk : Wv;
            const float* bias = (wv == 0) ? bq : (wv == 1) ? bk : bv;
            const float  sc   = (wv == 0) ? SCALE_QL : 1.0f;
            const int    col  = n0 + c;
            const float  vw   = (wv == 2) ? mask[b * NSEQ + col] * W_SCALE : 0.f;

#pragma unroll
            for (int tt = 0; tt < 4; ++tt) {
                const int t = tp * 4 + tt;
                f32x4 acc = {0.f, 0.f, 0.f, 0.f};
#pragma unroll
                for (int kk = 0; kk < 4; ++kk)
                    acc = mfma16(
                        cvt8(W + (t * 16 + c) * DM + kk * 32 + quad * 8, sc),
                        xf[kk], acc);
                if (wv == 2) {
#pragma unroll
                    for (int r = 0; r < 4; ++r)
                        Vt[((b * NH + t) * DK + quad * 4 + r) * NSEQ + col] =
                            f2bf((acc[r] + bias[t * 16 + quad * 4 + r]) * vw);
                } else {
                    u16x4 pk;
#pragma unroll
                    for (int r = 0; r < 4; ++r)
                        pk[r] = f2bf(acc[r] + bias[t * 16 + quad * 4 + r] * sc);
                    *reinterpret_cast<u16x4*>(
                        (wv == 0 ? Q : Kb) +
                        ((size_t)(b * NH + t) * NSEQ + col) * DK + quad * 4) = pk;
                }
            }
        } else {
            // side job: WfcB (16 elems/block), wb (8 elems/block)
            if (lane < 16) WfcB[bid * 16 + lane] = f2bf(Wfc[bid * 16 + lane]);
            if (lane < 8)
                wb[bid * 8 + lane] = f2bf(mask[bid * 8 + lane] * W_SCALE);
        }
    }

    grid_barrier(cnt, 1024);

    // ======================= phase 2: attention =============================
    // 2 q-tiles per block, serial. 4 waves = 4 kv quarters, 64 kv/iter.
    for (int i = 0; i < 2; ++i) {
        if (i) __syncthreads();            // smem reuse across q-tiles
        const int qt = bid * 2 + i;
        const int b  = qt >> 9;
        const int h  = (qt >> 6) & 7;
        const int n0 = (qt & 63) << 5;
        const int bh = b * NH + h;
        const int w  = wv;

        const u16x8 uq = *reinterpret_cast<const u16x8*>(
            Q + ((size_t)bh * NSEQ + n0 + q32) * DK + 8 * hi);

        const unsigned short* Kp = Kb + (size_t)bh * NSEQ * DK + 8 * hi;
        const unsigned short* Vp = Vt + ((size_t)bh * DK + c) * NSEQ + 8 * quad;
        const unsigned short* wp = wb + b * NSEQ + 8 * quad;

        char* pbase = smem + w * 4352;
        char* wrow  = pbase + q32 * 136 + 8 * hi;
        const char* rrow0 = pbase + c * 136 + 16 * quad;
        const char* rrow1 = pbase + (c + 16) * 136 + 16 * quad;

        f32x4 o0 = {0.f, 0.f, 0.f, 0.f}, o1 = {0.f, 0.f, 0.f, 0.f};
        f32x4 l0 = {0.f, 0.f, 0.f, 0.f}, l1 = {0.f, 0.f, 0.f, 0.f};
        const f32x16 z16 = {};
        const int kvb = w * (NSEQ / 4);

        u16x8 nk0 = *reinterpret_cast<const u16x8*>(Kp + (size_t)(kvb + q32) * DK);
        u16x8 nk1 = *reinterpret_cast<const u16x8*>(Kp + (size_t)(kvb + 32 + q32) * DK);

        for (int it = 0; it < 8; ++it) {
            const int kv0 = kvb + it * 64;
            const u16x8 uk0 = nk0, uk1 = nk1;
            if (it < 7) {
                nk0 = *reinterpret_cast<const u16x8*>(
                    Kp + (size_t)(kv0 + 64 + q32) * DK);
                nk1 = *reinterpret_cast<const u16x8*>(
                    Kp + (size_t)(kv0 + 96 + q32) * DK);
            }
            f32x16 S0 = mfma32(uk0, uq, z16);
            f32x16 S1 = mfma32(uk1, uq, z16);

#pragma unroll
            for (int j = 0; j < 16; ++j) {
                S0[j] = exp2_(S0[j]);
                S1[j] = exp2_(S1[j]);
            }

#pragma unroll
            for (int g = 0; g < 4; ++g) {
                u32x2 d0 = {pack2bf(S0[4 * g], S0[4 * g + 1]),
                            pack2bf(S0[4 * g + 2], S0[4 * g + 3])};
                u32x2 d1 = {pack2bf(S1[4 * g], S1[4 * g + 1]),
                            pack2bf(S1[4 * g + 2], S1[4 * g + 3])};
                *reinterpret_cast<u32x2*>(wrow + 16 * g) = d0;
                *reinterpret_cast<u32x2*>(wrow + 64 + 16 * g) = d1;
            }

#pragma unroll
            for (int t = 0; t < 2; ++t) {
                const u16x8 uv  = *reinterpret_cast<const u16x8*>(Vp + kv0 + 32 * t);
                const u16x8 uw  = *reinterpret_cast<const u16x8*>(wp + kv0 + 32 * t);
                const u16x8 up0 = *reinterpret_cast<const u16x8*>(rrow0 + 64 * t);
                const u16x8 up1 = *reinterpret_cast<const u16x8*>(rrow1 + 64 * t);
                o0 = mfma16(uv, up0, o0);
                o1 = mfma16(uv, up1, o1);
                l0 = mfma16(uw, up0, l0);
                l1 = mfma16(uw, up1, l1);
            }
        }

        __syncthreads();                   // all P reads done; reuse smem
        float* Lsm = reinterpret_cast<float*>(smem);
        float* Osm = reinterpret_cast<float*>(smem + 512);
        Lsm[w * 32 + c]      = l0[0];
        Lsm[w * 32 + 16 + c] = l1[0];
        *reinterpret_cast<f32x4*>(Osm + w * 640 + c * 20 + 4 * quad)        = o0;
        *reinterpret_cast<f32x4*>(Osm + w * 640 + (c + 16) * 20 + 4 * quad) = o1;
        __syncthreads();

        const int q   = tid >> 3;
        const int dk2 = (tid & 7) * 2;
        const float l = Lsm[q] + Lsm[32 + q] + Lsm[64 + q] + Lsm[96 + q];
        const float* Oq = Osm + q * 20 + dk2;
        const float v0 = Oq[0] + Oq[640] + Oq[1280] + Oq[1920];
        const float v1 = Oq[1] + Oq[641] + Oq[1281] + Oq[1921];
        const float inv = 1.0f / l;
        *reinterpret_cast<unsigned int*>(
            AO + ((size_t)(b * NSEQ) + n0 + q) * DM + h * DK + dk2) =
            pack2bf(v0 * inv, v1 * inv);
    }

    grid_barrier(cnt, 2048);

    // ======================= phase 3: FC + transpose ========================
    {
        const int b  = bid >> 8;
        const int n0 = ((bid >> 1) & 127) << 4;
        const int t  = (bid & 1) * 4 + wv;

        u16x8 af[4];
#pragma unroll
        for (int kk = 0; kk < 4; ++kk)
            af[kk] = *reinterpret_cast<const u16x8*>(
                AO + ((size_t)(b * NSEQ) + n0 + c) * DM + kk * 32 + quad * 8);

        f32x4 acc = {0.f, 0.f, 0.f, 0.f};
#pragma unroll
        for (int kk = 0; kk < 4; ++kk)
            acc = mfma16(*reinterpret_cast<const u16x8*>(
                             WfcB + (t * 16 + c) * DM + kk * 32 + quad * 8),
                         af[kk], acc);
#pragma unroll
        for (int r = 0; r < 4; ++r)
            out[(size_t)(b * DM + t * 16 + quad * 4 + r) * NSEQ + n0 + c] =
                acc[r] + bfc[t * 16 + quad * 4 + r];
    }
}

// ---------------------------------------------------------------------------
extern "C" void kernel_launch(void* const* d_in, const int* in_sizes, int n_in,
                              void* d_out, int out_size, void* d_ws, size_t ws_size,
                              hipStream_t stream)
{
    const float* x    = (const float*)d_in[0];
    const float* mask = (const float*)d_in[1];
    const float* Wq   = (const float*)d_in[2];
    const float* bq   = (const float*)d_in[3];
    const float* Wk   = (const float*)d_in[4];
    const float* bk   = (const float*)d_in[5];
    const float* Wv   = (const float*)d_in[6];
    const float* bv   = (const float*)d_in[7];
    const float* Wfc  = (const float*)d_in[8];
    const float* bfc  = (const float*)d_in[9];
    float* out = (float*)d_out;

    const size_t QKV_ELEMS = (size_t)BSZ * NH * NSEQ * DK;  // 1,048,576
    unsigned short* Q    = (unsigned short*)d_ws;
    unsigned short* Kb   = Q + QKV_ELEMS;
    unsigned short* Vt   = Kb + QKV_ELEMS;
    unsigned short* AO   = Vt + QKV_ELEMS;
    unsigned short* WfcB = AO + QKV_ELEMS;
    unsigned short* wb   = WfcB + DM * DM;
    unsigned*       cnt  = (unsigned*)(wb + BSZ * NSEQ);

    // barrier counter must start at 0 (ws is poisoned to 0xAA by the harness)
    hipMemsetAsync(cnt, 0, sizeof(unsigned), stream);

    k_fused<<<1024, 256, 0, stream>>>(x, Wq, bq, Wk, bk, Wv, bv, Wfc, bfc, mask,
                                      out, Q, Kb, Vt, AO, WfcB, wb, cnt);
}

// Round 8
// 359.716 us; speedup vs baseline: 1.6196x; 1.6196x over previous
//
#include <hip/hip_runtime.h>
#include <stdint.h>

#define BSZ  4
#define NSEQ 2048
#define DM   128
#define NH   8
#define DK   16
#define LOG2E 1.4426950408889634f
// LOG2E / sqrt(128): folded into Wq/bq so scores exit QK^T in log2 domain
#define SCALE_QL 0.1275156338341935f
// mask weight: w = mask * 2^-18 (exact in bf16); folded into V' and the
// l-reduction A-operand. p = exp2(S) stays <= ~2^10, l ~ 1e-2 -> safe fp32.
#define W_SCALE 3.814697265625e-6f

typedef __bf16          bf16x8v __attribute__((ext_vector_type(8)));
typedef float           f32x2   __attribute__((ext_vector_type(2)));
typedef float           f32x4   __attribute__((ext_vector_type(4)));
typedef float           f32x16  __attribute__((ext_vector_type(16)));
typedef unsigned short  u16x8   __attribute__((ext_vector_type(8)));
typedef unsigned short  u16x4   __attribute__((ext_vector_type(4)));
typedef unsigned int    u32x2   __attribute__((ext_vector_type(2)));
typedef unsigned int    u32x4   __attribute__((ext_vector_type(4)));

__device__ __forceinline__ unsigned short f2bf(float f) {
    unsigned u = __float_as_uint(f);
    u = (u + 0x7fffu + ((u >> 16) & 1u)) >> 16;
    return (unsigned short)u;
}

__device__ __forceinline__ unsigned int pack2bf(float a, float b) {
#if __has_builtin(__builtin_amdgcn_cvt_pk_bf16_f32)
    typedef __bf16 bf16x2 __attribute__((ext_vector_type(2)));
    bf16x2 v = __builtin_amdgcn_cvt_pk_bf16_f32(a, b);
    return __builtin_bit_cast(unsigned int, v);
#else
    return (unsigned)f2bf(a) | ((unsigned)f2bf(b) << 16);
#endif
}

__device__ __forceinline__ float exp2_(float x) {
#if __has_builtin(__builtin_amdgcn_exp2f)
    return __builtin_amdgcn_exp2f(x);
#else
    return exp2f(x);
#endif
}

// load 8 consecutive f32, scale, convert -> u16x8 bf16 fragment
__device__ __forceinline__ u16x8 cvt8(const float* p, float sc) {
    const f32x4 a = *reinterpret_cast<const f32x4*>(p);
    const f32x4 b = *reinterpret_cast<const f32x4*>(p + 4);
    u32x4 u = {pack2bf(a[0] * sc, a[1] * sc), pack2bf(a[2] * sc, a[3] * sc),
               pack2bf(b[0] * sc, b[1] * sc), pack2bf(b[2] * sc, b[3] * sc)};
    return __builtin_bit_cast(u16x8, u);
}

__device__ __forceinline__ f32x4 mfma16(u16x8 a, u16x8 b, f32x4 c) {
    return __builtin_amdgcn_mfma_f32_16x16x32_bf16(
        __builtin_bit_cast(bf16x8v, a), __builtin_bit_cast(bf16x8v, b), c, 0, 0, 0);
}
__device__ __forceinline__ f32x16 mfma32(u16x8 a, u16x8 b, f32x16 c) {
    return __builtin_amdgcn_mfma_f32_32x32x16_bf16(
        __builtin_bit_cast(bf16x8v, a), __builtin_bit_cast(bf16x8v, b), c, 0, 0, 0);
}

// Software grid barrier, v2. Safe: grid=1024 blocks, __launch_bounds__(256,4)
// -> 4 blocks/CU x 256 CU co-resident (LDS 17.4KB, VGPR<=128).
// KEY FIX vs v1: poll with RELAXED agent loads (plain sc0 L2 read, no cache
// maintenance). v1's ACQUIRE poll emitted buffer_inv (L1+L2 invalidate) per
// iteration -> device-wide invalidate storm, ~450us of barrier time.
// One __threadfence (release) before arrival publishes our XCD-L2 lines;
// one __threadfence (acquire side) after spin-exit invalidates once.
__device__ __forceinline__ void grid_barrier(unsigned* cnt, unsigned target) {
    __syncthreads();                 // all block's stores at L2 (vmcnt drain)
    if (threadIdx.x == 0) {
        __threadfence();             // publish: L2 writeback, once
        __hip_atomic_fetch_add(cnt, 1u, __ATOMIC_RELAXED,
                               __HIP_MEMORY_SCOPE_AGENT);
        while (__hip_atomic_load(cnt, __ATOMIC_RELAXED,
                                 __HIP_MEMORY_SCOPE_AGENT) < target) {
            __builtin_amdgcn_s_sleep(32);
        }
        __threadfence();             // acquire: invalidate stale L1/L2, once
    }
    __syncthreads();
}

// ---------------------------------------------------------------------------
// Fused qkv -> attn -> fc, single dispatch, 1024 blocks x 256 threads.
// ---------------------------------------------------------------------------
__global__ __launch_bounds__(256, 4) void k_fused(
    const float* __restrict__ x,
    const float* __restrict__ Wq, const float* __restrict__ bq,
    const float* __restrict__ Wk, const float* __restrict__ bk,
    const float* __restrict__ Wv, const float* __restrict__ bv,
    const float* __restrict__ Wfc, const float* __restrict__ bfc,
    const float* __restrict__ mask,
    float* __restrict__ out,
    unsigned short* __restrict__ Q, unsigned short* __restrict__ Kb,
    unsigned short* __restrict__ Vt, unsigned short* __restrict__ AO,
    unsigned short* __restrict__ WfcB, unsigned short* __restrict__ wb,
    unsigned* __restrict__ cnt)
{
    __shared__ __align__(16) char smem[17408];
    const int tid  = threadIdx.x;
    const int bid  = blockIdx.x;
    const int lane = tid & 63;
    const int wv   = tid >> 6;
    const int c    = lane & 15;
    const int quad = lane >> 4;
    const int hi   = lane >> 5;
    const int q32  = lane & 31;

    // ======================= phase 1: QKV projection ========================
    // block = (b, ntile16, t-half): stage x[b][:][16n] once, 3 mat-waves
    // each compute 4 d'-tiles; wave 3 converts Wfc + builds wb.
    {
        const int b   = bid >> 8;
        const int nt  = (bid >> 1) & 127;
        const int tp  = bid & 1;
        const int n0  = nt << 4;
        float* xs = reinterpret_cast<float*>(smem);   // [128][18] f32 (stride 18)

        // stage x: 128 rows x 16 f32, f32x2 chunks
        for (int k = tid; k < 1024; k += 256) {
            const int d = k >> 3, p = (k & 7) << 1;
            *reinterpret_cast<f32x2*>(&xs[d * 18 + p]) =
                *reinterpret_cast<const f32x2*>(
                    x + (size_t)(b * DM + d) * NSEQ + n0 + p);
        }
        __syncthreads();

        if (wv < 3) {
            // B-frag gather from LDS: B[k=d][n=c]; stride 18 -> 2-way only
            u16x8 xf[4];
#pragma unroll
            for (int kk = 0; kk < 4; ++kk) {
                float f[8];
#pragma unroll
                for (int j = 0; j < 8; ++j)
                    f[j] = xs[(kk * 32 + quad * 8 + j) * 18 + c];
                u32x4 u = {pack2bf(f[0], f[1]), pack2bf(f[2], f[3]),
                           pack2bf(f[4], f[5]), pack2bf(f[6], f[7])};
                xf[kk] = __builtin_bit_cast(u16x8, u);
            }

            const float* W    = (wv == 0) ? Wq : (wv == 1) ? Wk : Wv;
            const float* bias = (wv == 0) ? bq : (wv == 1) ? bk : bv;
            const float  sc   = (wv == 0) ? SCALE_QL : 1.0f;
            const int    col  = n0 + c;
            const float  vw   = (wv == 2) ? mask[b * NSEQ + col] * W_SCALE : 0.f;

#pragma unroll
            for (int tt = 0; tt < 4; ++tt) {
                const int t = tp * 4 + tt;
                f32x4 acc = {0.f, 0.f, 0.f, 0.f};
#pragma unroll
                for (int kk = 0; kk < 4; ++kk)
                    acc = mfma16(
                        cvt8(W + (t * 16 + c) * DM + kk * 32 + quad * 8, sc),
                        xf[kk], acc);
                if (wv == 2) {
#pragma unroll
                    for (int r = 0; r < 4; ++r)
                        Vt[((b * NH + t) * DK + quad * 4 + r) * NSEQ + col] =
                            f2bf((acc[r] + bias[t * 16 + quad * 4 + r]) * vw);
                } else {
                    u16x4 pk;
#pragma unroll
                    for (int r = 0; r < 4; ++r)
                        pk[r] = f2bf(acc[r] + bias[t * 16 + quad * 4 + r] * sc);
                    *reinterpret_cast<u16x4*>(
                        (wv == 0 ? Q : Kb) +
                        ((size_t)(b * NH + t) * NSEQ + col) * DK + quad * 4) = pk;
                }
            }
        } else {
            // side job: WfcB (16 elems/block), wb (8 elems/block)
            if (lane < 16) WfcB[bid * 16 + lane] = f2bf(Wfc[bid * 16 + lane]);
            if (lane < 8)
                wb[bid * 8 + lane] = f2bf(mask[bid * 8 + lane] * W_SCALE);
        }
    }

    grid_barrier(cnt, 1024);

    // ======================= phase 2: attention =============================
    // 2 q-tiles per block, serial. 4 waves = 4 kv quarters, 64 kv/iter.
    for (int i = 0; i < 2; ++i) {
        if (i) __syncthreads();            // smem reuse across q-tiles
        const int qt = bid * 2 + i;
        const int b  = qt >> 9;
        const int h  = (qt >> 6) & 7;
        const int n0 = (qt & 63) << 5;
        const int bh = b * NH + h;
        const int w  = wv;

        const u16x8 uq = *reinterpret_cast<const u16x8*>(
            Q + ((size_t)bh * NSEQ + n0 + q32) * DK + 8 * hi);

        const unsigned short* Kp = Kb + (size_t)bh * NSEQ * DK + 8 * hi;
        const unsigned short* Vp = Vt + ((size_t)bh * DK + c) * NSEQ + 8 * quad;
        const unsigned short* wp = wb + b * NSEQ + 8 * quad;

        char* pbase = smem + w * 4352;
        char* wrow  = pbase + q32 * 136 + 8 * hi;
        const char* rrow0 = pbase + c * 136 + 16 * quad;
        const char* rrow1 = pbase + (c + 16) * 136 + 16 * quad;

        f32x4 o0 = {0.f, 0.f, 0.f, 0.f}, o1 = {0.f, 0.f, 0.f, 0.f};
        f32x4 l0 = {0.f, 0.f, 0.f, 0.f}, l1 = {0.f, 0.f, 0.f, 0.f};
        const f32x16 z16 = {};
        const int kvb = w * (NSEQ / 4);

        u16x8 nk0 = *reinterpret_cast<const u16x8*>(Kp + (size_t)(kvb + q32) * DK);
        u16x8 nk1 = *reinterpret_cast<const u16x8*>(Kp + (size_t)(kvb + 32 + q32) * DK);

        for (int it = 0; it < 8; ++it) {
            const int kv0 = kvb + it * 64;
            const u16x8 uk0 = nk0, uk1 = nk1;
            if (it < 7) {
                nk0 = *reinterpret_cast<const u16x8*>(
                    Kp + (size_t)(kv0 + 64 + q32) * DK);
                nk1 = *reinterpret_cast<const u16x8*>(
                    Kp + (size_t)(kv0 + 96 + q32) * DK);
            }
            f32x16 S0 = mfma32(uk0, uq, z16);
            f32x16 S1 = mfma32(uk1, uq, z16);

#pragma unroll
            for (int j = 0; j < 16; ++j) {
                S0[j] = exp2_(S0[j]);
                S1[j] = exp2_(S1[j]);
            }

#pragma unroll
            for (int g = 0; g < 4; ++g) {
                u32x2 d0 = {pack2bf(S0[4 * g], S0[4 * g + 1]),
                            pack2bf(S0[4 * g + 2], S0[4 * g + 3])};
                u32x2 d1 = {pack2bf(S1[4 * g], S1[4 * g + 1]),
                            pack2bf(S1[4 * g + 2], S1[4 * g + 3])};
                *reinterpret_cast<u32x2*>(wrow + 16 * g) = d0;
                *reinterpret_cast<u32x2*>(wrow + 64 + 16 * g) = d1;
            }

#pragma unroll
            for (int t = 0; t < 2; ++t) {
                const u16x8 uv  = *reinterpret_cast<const u16x8*>(Vp + kv0 + 32 * t);
                const u16x8 uw  = *reinterpret_cast<const u16x8*>(wp + kv0 + 32 * t);
                const u16x8 up0 = *reinterpret_cast<const u16x8*>(rrow0 + 64 * t);
                const u16x8 up1 = *reinterpret_cast<const u16x8*>(rrow1 + 64 * t);
                o0 = mfma16(uv, up0, o0);
                o1 = mfma16(uv, up1, o1);
                l0 = mfma16(uw, up0, l0);
                l1 = mfma16(uw, up1, l1);
            }
        }

        __syncthreads();                   // all P reads done; reuse smem
        float* Lsm = reinterpret_cast<float*>(smem);
        float* Osm = reinterpret_cast<float*>(smem + 512);
        Lsm[w * 32 + c]      = l0[0];
        Lsm[w * 32 + 16 + c] = l1[0];
        *reinterpret_cast<f32x4*>(Osm + w * 640 + c * 20 + 4 * quad)        = o0;
        *reinterpret_cast<f32x4*>(Osm + w * 640 + (c + 16) * 20 + 4 * quad) = o1;
        __syncthreads();

        const int q   = tid >> 3;
        const int dk2 = (tid & 7) * 2;
        const float l = Lsm[q] + Lsm[32 + q] + Lsm[64 + q] + Lsm[96 + q];
        const float* Oq = Osm + q * 20 + dk2;
        const float v0 = Oq[0] + Oq[640] + Oq[1280] + Oq[1920];
        const float v1 = Oq[1] + Oq[641] + Oq[1281] + Oq[1921];
        const float inv = 1.0f / l;
        *reinterpret_cast<unsigned int*>(
            AO + ((size_t)(b * NSEQ) + n0 + q) * DM + h * DK + dk2) =
            pack2bf(v0 * inv, v1 * inv);
    }

    grid_barrier(cnt, 2048);

    // ======================= phase 3: FC + transpose ========================
    {
        const int b  = bid >> 8;
        const int n0 = ((bid >> 1) & 127) << 4;
        const int t  = (bid & 1) * 4 + wv;

        u16x8 af[4];
#pragma unroll
        for (int kk = 0; kk < 4; ++kk)
            af[kk] = *reinterpret_cast<const u16x8*>(
                AO + ((size_t)(b * NSEQ) + n0 + c) * DM + kk * 32 + quad * 8);

        f32x4 acc = {0.f, 0.f, 0.f, 0.f};
#pragma unroll
        for (int kk = 0; kk < 4; ++kk)
            acc = mfma16(*reinterpret_cast<const u16x8*>(
                             WfcB + (t * 16 + c) * DM + kk * 32 + quad * 8),
                         af[kk], acc);
#pragma unroll
        for (int r = 0; r < 4; ++r)
            out[(size_t)(b * DM + t * 16 + quad * 4 + r) * NSEQ + n0 + c] =
                acc[r] + bfc[t * 16 + quad * 4 + r];
    }
}

// ---------------------------------------------------------------------------
extern "C" void kernel_launch(void* const* d_in, const int* in_sizes, int n_in,
                              void* d_out, int out_size, void* d_ws, size_t ws_size,
                              hipStream_t stream)
{
    const float* x    = (const float*)d_in[0];
    const float* mask = (const float*)d_in[1];
    const float* Wq   = (const float*)d_in[2];
    const float* bq   = (const float*)d_in[3];
    const float* Wk   = (const float*)d_in[4];
    const float* bk   = (const float*)d_in[5];
    const float* Wv   = (const float*)d_in[6];
    const float* bv   = (const float*)d_in[7];
    const float* Wfc  = (const float*)d_in[8];
    const float* bfc  = (const float*)d_in[9];
    float* out = (float*)d_out;

    const size_t QKV_ELEMS = (size_t)BSZ * NH * NSEQ * DK;  // 1,048,576
    unsigned short* Q    = (unsigned short*)d_ws;
    unsigned short* Kb   = Q + QKV_ELEMS;
    unsigned short* Vt   = Kb + QKV_ELEMS;
    unsigned short* AO   = Vt + QKV_ELEMS;
    unsigned short* WfcB = AO + QKV_ELEMS;
    unsigned short* wb   = WfcB + DM * DM;
    unsigned*       cnt  = (unsigned*)(wb + BSZ * NSEQ);

    // barrier counter must start at 0 (ws is poisoned to 0xAA by the harness)
    hipMemsetAsync(cnt, 0, sizeof(unsigned), stream);

    k_fused<<<1024, 256, 0, stream>>>(x, Wq, bq, Wk, bk, Wv, bv, Wfc, bfc, mask,
                                      out, Q, Kb, Vt, AO, WfcB, wb, cnt);
}

// Round 9
// 134.130 us; speedup vs baseline: 4.3434x; 2.6818x over previous
//
#include <hip/hip_runtime.h>
#include <stdint.h>

#define BSZ  4
#define NSEQ 2048
#define DM   128
#define NH   8
#define DK   16
#define LOG2E 1.4426950408889634f
// LOG2E / sqrt(128): folded into Wq/bq so scores exit QK^T in log2 domain
#define SCALE_QL 0.1275156338341935f
// mask weight: w = mask * 2^-18 (exact in bf16); folded into V' and the
// l-reduction A-operand. p = exp2(S) stays <= ~2^10, l ~ 1e-2 -> safe fp32.
#define W_SCALE 3.814697265625e-6f

typedef __bf16          bf16x8v __attribute__((ext_vector_type(8)));
typedef float           f32x4   __attribute__((ext_vector_type(4)));
typedef float           f32x16  __attribute__((ext_vector_type(16)));
typedef unsigned short  u16x8   __attribute__((ext_vector_type(8)));
typedef unsigned short  u16x4   __attribute__((ext_vector_type(4)));
typedef unsigned int    u32x2   __attribute__((ext_vector_type(2)));
typedef unsigned int    u32x4   __attribute__((ext_vector_type(4)));

__device__ __forceinline__ unsigned short f2bf(float f) {
    unsigned u = __float_as_uint(f);
    u = (u + 0x7fffu + ((u >> 16) & 1u)) >> 16;
    return (unsigned short)u;
}

__device__ __forceinline__ unsigned int pack2bf(float a, float b) {
#if __has_builtin(__builtin_amdgcn_cvt_pk_bf16_f32)
    typedef __bf16 bf16x2 __attribute__((ext_vector_type(2)));
    bf16x2 v = __builtin_amdgcn_cvt_pk_bf16_f32(a, b);
    return __builtin_bit_cast(unsigned int, v);
#else
    return (unsigned)f2bf(a) | ((unsigned)f2bf(b) << 16);
#endif
}

__device__ __forceinline__ float exp2_(float x) {
#if __has_builtin(__builtin_amdgcn_exp2f)
    return __builtin_amdgcn_exp2f(x);
#else
    return exp2f(x);
#endif
}

// load 8 consecutive f32, scale, convert -> u16x8 bf16 fragment
__device__ __forceinline__ u16x8 cvt8(const float* p, float sc) {
    const f32x4 a = *reinterpret_cast<const f32x4*>(p);
    const f32x4 b = *reinterpret_cast<const f32x4*>(p + 4);
    u32x4 u = {pack2bf(a[0] * sc, a[1] * sc), pack2bf(a[2] * sc, a[3] * sc),
               pack2bf(b[0] * sc, b[1] * sc), pack2bf(b[2] * sc, b[3] * sc)};
    return __builtin_bit_cast(u16x8, u);
}

__device__ __forceinline__ f32x4 mfma16(u16x8 a, u16x8 b, f32x4 c) {
    return __builtin_amdgcn_mfma_f32_16x16x32_bf16(
        __builtin_bit_cast(bf16x8v, a), __builtin_bit_cast(bf16x8v, b), c, 0, 0, 0);
}
__device__ __forceinline__ f32x16 mfma32(u16x8 a, u16x8 b, f32x16 c) {
    return __builtin_amdgcn_mfma_f32_32x32x16_bf16(
        __builtin_bit_cast(bf16x8v, a), __builtin_bit_cast(bf16x8v, b), c, 0, 0, 0);
}

// ---------------------------------------------------------------------------
// k_qkv: C^T-form projection, x-tile staged in LDS (coalesced f32x4 loads).
// grid = b(4) x n-tile32(64), 768 threads = 12 waves = mat(3) x nsub(2) x th(2).
// V is scaled by w = mask*2^-18 at generation (V' = V*w).
// Side-job: WfcB = bf16(Wfc); wb = bf16(mask*2^-18).
// ---------------------------------------------------------------------------
__global__ __launch_bounds__(768) void k_qkv(
    const float* __restrict__ x,
    const float* __restrict__ Wq, const float* __restrict__ bq,
    const float* __restrict__ Wk, const float* __restrict__ bk,
    const float* __restrict__ Wv, const float* __restrict__ bv,
    const float* __restrict__ Wfc, const float* __restrict__ mask,
    unsigned short* __restrict__ Q, unsigned short* __restrict__ Kb,
    unsigned short* __restrict__ Vt,
    unsigned short* __restrict__ WfcB, unsigned short* __restrict__ wb)
{
    __shared__ __align__(16) float xs[DM * 36];   // 32 n + 4 pad
    const int tid = threadIdx.x;

    // side job (consumed by LATER kernels only)
    const int gt = blockIdx.x * 768 + tid;
    if (gt < DM * DM) {
        WfcB[gt] = f2bf(Wfc[gt]);
    } else if (gt < DM * DM + BSZ * NSEQ) {
        const int i = gt - DM * DM;
        wb[i] = f2bf(mask[i] * W_SCALE);
    }

    const int b  = blockIdx.x >> 6;
    const int n0 = (blockIdx.x & 63) << 5;

    // stage x[b][0..128][n0..n0+32] -> xs[d*36 + j], fully coalesced
#pragma unroll
    for (int i = tid; i < 1024; i += 768) {
        const int d = i >> 3, c4 = (i & 7) << 2;
        *reinterpret_cast<f32x4*>(&xs[d * 36 + c4]) =
            *reinterpret_cast<const f32x4*>(x + (size_t)(b * DM + d) * NSEQ + n0 + c4);
    }
    __syncthreads();

    const int lane = tid & 63;
    const int wv   = tid >> 6;          // 0..11
    const int mat  = wv >> 2;           // 0..2
    const int nt   = (wv >> 1) & 1;     // n subtile
    const int th   = wv & 1;            // t half
    const int c    = lane & 15;
    const int quad = lane >> 4;
    const int col  = n0 + nt * 16 + c;

    // B-frag from LDS: B[k=d][n=c]
    u16x8 xf[4];
#pragma unroll
    for (int kk = 0; kk < 4; ++kk) {
        float f[8];
#pragma unroll
        for (int j = 0; j < 8; ++j)
            f[j] = xs[(kk * 32 + quad * 8 + j) * 36 + nt * 16 + c];
        u32x4 u = {pack2bf(f[0], f[1]), pack2bf(f[2], f[3]),
                   pack2bf(f[4], f[5]), pack2bf(f[6], f[7])};
        xf[kk] = __builtin_bit_cast(u16x8, u);
    }

    const float* W    = (mat == 0) ? Wq : (mat == 1) ? Wk : Wv;
    const float* bias = (mat == 0) ? bq : (mat == 1) ? bk : bv;
    const float  sc   = (mat == 0) ? SCALE_QL : 1.0f;
    const float  vw   = (mat == 2) ? mask[b * NSEQ + col] * W_SCALE : 0.f;

#pragma unroll
    for (int tt = 0; tt < 4; ++tt) {
        const int t = th * 4 + tt;
        f32x4 acc = {0.f, 0.f, 0.f, 0.f};
#pragma unroll
        for (int kk = 0; kk < 4; ++kk)
            acc = mfma16(cvt8(W + (t * 16 + c) * DM + kk * 32 + quad * 8, sc),
                         xf[kk], acc);
        if (mat == 2) {
#pragma unroll
            for (int r = 0; r < 4; ++r)
                Vt[((b * NH + t) * DK + quad * 4 + r) * NSEQ + col] =
                    f2bf((acc[r] + bias[t * 16 + quad * 4 + r]) * vw);
        } else {
            u16x4 pk;
#pragma unroll
            for (int r = 0; r < 4; ++r)
                pk[r] = f2bf(acc[r] + bias[t * 16 + quad * 4 + r] * sc);
            *reinterpret_cast<u16x4*>(
                (mat == 0 ? Q : Kb) + ((size_t)(b * NH + t) * NSEQ + col) * DK +
                quad * 4) = pk;
        }
    }
}

// ---------------------------------------------------------------------------
// k_attn v3: fixed-scale flash attention, DUAL q-tile per block (ILP-2).
// Block = q-tiles (2j, 2j+1) -- same (b,h), n0 and n0+32 -> shared K/V/w
// loads. 4 waves = 4 kv quarters, 64 kv/iter, two independent dependency
// chains per wave (S_A, S_B) so MFMA of one overlaps exp2/pack/LDS of the
// other. Per-wave double staging (A,B) = 34.8 KB LDS -> 4 blocks/CU.
// ---------------------------------------------------------------------------
__global__ __launch_bounds__(256, 4) void k_attn(
    const unsigned short* __restrict__ Q,
    const unsigned short* __restrict__ Kb,
    const unsigned short* __restrict__ Vt,
    const unsigned short* __restrict__ wb,
    unsigned short* __restrict__ AO)
{
    __shared__ __align__(16) char smem[34816];
    const int tid  = threadIdx.x;
    const int lane = tid & 63;
    const int w    = tid >> 6;      // kv quarter
    const int q32  = lane & 31;
    const int c    = lane & 15;
    const int quad = lane >> 4;
    const int hi   = lane >> 5;

    const int qt0 = blockIdx.x * 2;            // even tile; odd = +1
    const int b   = qt0 >> 9;
    const int h   = (qt0 >> 6) & 7;
    const int n0  = (qt0 & 63) << 5;           // tile A; tile B at n0+32
    const int bh  = b * NH + h;

    // Q B-frags for both tiles (prescaled to log2 domain)
    const u16x8 uqA = *reinterpret_cast<const u16x8*>(
        Q + ((size_t)bh * NSEQ + n0 + q32) * DK + 8 * hi);
    const u16x8 uqB = *reinterpret_cast<const u16x8*>(
        Q + ((size_t)bh * NSEQ + n0 + 32 + q32) * DK + 8 * hi);

    const unsigned short* Kp = Kb + (size_t)bh * NSEQ * DK + 8 * hi;
    const unsigned short* Vp = Vt + ((size_t)bh * DK + c) * NSEQ + 8 * quad;
    const unsigned short* wp = wb + b * NSEQ + 8 * quad;

    // per-wave staging: tile A at +0, tile B at +4352 (32 rows x 136 B each)
    char* pbA = smem + w * 8704;
    char* pbB = pbA + 4352;
    char* wrowA = pbA + q32 * 136 + 8 * hi;
    char* wrowB = pbB + q32 * 136 + 8 * hi;
    const char* rA0 = pbA + c * 136 + 16 * quad;
    const char* rA1 = pbA + (c + 16) * 136 + 16 * quad;
    const char* rB0 = pbB + c * 136 + 16 * quad;
    const char* rB1 = pbB + (c + 16) * 136 + 16 * quad;

    f32x4 oA0 = {0.f, 0.f, 0.f, 0.f}, oA1 = {0.f, 0.f, 0.f, 0.f};
    f32x4 oB0 = {0.f, 0.f, 0.f, 0.f}, oB1 = {0.f, 0.f, 0.f, 0.f};
    f32x4 lA0 = {0.f, 0.f, 0.f, 0.f}, lA1 = {0.f, 0.f, 0.f, 0.f};
    f32x4 lB0 = {0.f, 0.f, 0.f, 0.f}, lB1 = {0.f, 0.f, 0.f, 0.f};
    const f32x16 z16 = {};
    const int kvb = w * (NSEQ / 4);

    u16x8 nk0 = *reinterpret_cast<const u16x8*>(Kp + (size_t)(kvb + q32) * DK);
    u16x8 nk1 = *reinterpret_cast<const u16x8*>(Kp + (size_t)(kvb + 32 + q32) * DK);

    for (int it = 0; it < 8; ++it) {
        const int kv0 = kvb + it * 64;
        const u16x8 uk0 = nk0, uk1 = nk1;
        if (it < 7) {
            nk0 = *reinterpret_cast<const u16x8*>(Kp + (size_t)(kv0 + 64 + q32) * DK);
            nk1 = *reinterpret_cast<const u16x8*>(Kp + (size_t)(kv0 + 96 + q32) * DK);
        }

        // --- kv sub-block 0 (rows kv0..kv0+31), both tiles in flight ---
        {
            f32x16 SA = mfma32(uk0, uqA, z16);
            f32x16 SB = mfma32(uk0, uqB, z16);
#pragma unroll
            for (int j = 0; j < 16; ++j) {
                SA[j] = exp2_(SA[j]);
                SB[j] = exp2_(SB[j]);
            }
#pragma unroll
            for (int g = 0; g < 4; ++g) {
                u32x2 dA = {pack2bf(SA[4 * g], SA[4 * g + 1]),
                            pack2bf(SA[4 * g + 2], SA[4 * g + 3])};
                u32x2 dB = {pack2bf(SB[4 * g], SB[4 * g + 1]),
                            pack2bf(SB[4 * g + 2], SB[4 * g + 3])};
                *reinterpret_cast<u32x2*>(wrowA + 16 * g) = dA;
                *reinterpret_cast<u32x2*>(wrowB + 16 * g) = dB;
            }
        }
        // --- kv sub-block 1 (rows kv0+32..kv0+63) ---
        {
            f32x16 SA = mfma32(uk1, uqA, z16);
            f32x16 SB = mfma32(uk1, uqB, z16);
#pragma unroll
            for (int j = 0; j < 16; ++j) {
                SA[j] = exp2_(SA[j]);
                SB[j] = exp2_(SB[j]);
            }
#pragma unroll
            for (int g = 0; g < 4; ++g) {
                u32x2 dA = {pack2bf(SA[4 * g], SA[4 * g + 1]),
                            pack2bf(SA[4 * g + 2], SA[4 * g + 3])};
                u32x2 dB = {pack2bf(SB[4 * g], SB[4 * g + 1]),
                            pack2bf(SB[4 * g + 2], SB[4 * g + 3])};
                *reinterpret_cast<u32x2*>(wrowA + 64 + 16 * g) = dA;
                *reinterpret_cast<u32x2*>(wrowB + 64 + 16 * g) = dB;
            }
        }

        // --- PV + l for both tiles; V/w fragments shared ---
#pragma unroll
        for (int t = 0; t < 2; ++t) {
            const u16x8 uv = *reinterpret_cast<const u16x8*>(Vp + kv0 + 32 * t);
            const u16x8 uw = *reinterpret_cast<const u16x8*>(wp + kv0 + 32 * t);
            const u16x8 upA0 = *reinterpret_cast<const u16x8*>(rA0 + 64 * t);
            const u16x8 upA1 = *reinterpret_cast<const u16x8*>(rA1 + 64 * t);
            const u16x8 upB0 = *reinterpret_cast<const u16x8*>(rB0 + 64 * t);
            const u16x8 upB1 = *reinterpret_cast<const u16x8*>(rB1 + 64 * t);
            oA0 = mfma16(uv, upA0, oA0);
            oB0 = mfma16(uv, upB0, oB0);
            oA1 = mfma16(uv, upA1, oA1);
            oB1 = mfma16(uv, upB1, oB1);
            lA0 = mfma16(uw, upA0, lA0);
            lB0 = mfma16(uw, upB0, lB0);
            lA1 = mfma16(uw, upA1, lA1);
            lB1 = mfma16(uw, upB1, lB1);
        }
    }

    // ---- plain-sum 4-way merge, both tiles (reuse staging LDS) ----
    __syncthreads();                       // all P reads done
    // tile i: Lsm at i*512 ([w][q] f32), Osm at 1024 + i*10240 ([w][q*20+dk])
    float* LsmA = reinterpret_cast<float*>(smem);
    float* LsmB = reinterpret_cast<float*>(smem + 512);
    float* OsmA = reinterpret_cast<float*>(smem + 1024);
    float* OsmB = reinterpret_cast<float*>(smem + 1024 + 10240);
    LsmA[w * 32 + c]      = lA0[0];
    LsmA[w * 32 + 16 + c] = lA1[0];
    LsmB[w * 32 + c]      = lB0[0];
    LsmB[w * 32 + 16 + c] = lB1[0];
    *reinterpret_cast<f32x4*>(OsmA + w * 640 + c * 20 + 4 * quad)        = oA0;
    *reinterpret_cast<f32x4*>(OsmA + w * 640 + (c + 16) * 20 + 4 * quad) = oA1;
    *reinterpret_cast<f32x4*>(OsmB + w * 640 + c * 20 + 4 * quad)        = oB0;
    *reinterpret_cast<f32x4*>(OsmB + w * 640 + (c + 16) * 20 + 4 * quad) = oB1;
    __syncthreads();

    const int q   = tid >> 3;              // 0..31
    const int dk2 = (tid & 7) * 2;         // 0,2,..,14
#pragma unroll
    for (int i = 0; i < 2; ++i) {
        const float* Lsm = i ? LsmB : LsmA;
        const float* Osm = i ? OsmB : OsmA;
        const float l = Lsm[q] + Lsm[32 + q] + Lsm[64 + q] + Lsm[96 + q];
        const float* Oq = Osm + q * 20 + dk2;
        const float v0 = Oq[0] + Oq[640] + Oq[1280] + Oq[1920];
        const float v1 = Oq[1] + Oq[641] + Oq[1281] + Oq[1921];
        const float inv = 1.0f / l;
        *reinterpret_cast<unsigned int*>(
            AO + ((size_t)(b * NSEQ) + n0 + i * 32 + q) * DM + h * DK + dk2) =
            pack2bf(v0 * inv, v1 * inv);
    }
}

// ---------------------------------------------------------------------------
// k_fc: C^T-form FC, output directly in (B, D, N).
// grid = b(4) x n-tile(128) x t-half(2), 4 waves, wave = one d'-tile.
// ---------------------------------------------------------------------------
__global__ __launch_bounds__(256) void k_fc(
    const unsigned short* __restrict__ AO,
    const unsigned short* __restrict__ WfcB, const float* __restrict__ bfc,
    float* __restrict__ out)
{
    const int lane = threadIdx.x & 63;
    const int w    = threadIdx.x >> 6;
    const int c    = lane & 15;
    const int quad = lane >> 4;
    const int b    = blockIdx.x >> 8;
    const int n0   = ((blockIdx.x >> 1) & 127) << 4;
    const int t    = (blockIdx.x & 1) * 4 + w;

    u16x8 af[4];
#pragma unroll
    for (int kk = 0; kk < 4; ++kk)
        af[kk] = *reinterpret_cast<const u16x8*>(
            AO + ((size_t)(b * NSEQ) + n0 + c) * DM + kk * 32 + quad * 8);

    f32x4 acc = {0.f, 0.f, 0.f, 0.f};
#pragma unroll
    for (int kk = 0; kk < 4; ++kk)
        acc = mfma16(*reinterpret_cast<const u16x8*>(
                         WfcB + (t * 16 + c) * DM + kk * 32 + quad * 8),
                     af[kk], acc);
#pragma unroll
    for (int r = 0; r < 4; ++r)
        out[(size_t)(b * DM + t * 16 + quad * 4 + r) * NSEQ + n0 + c] =
            acc[r] + bfc[t * 16 + quad * 4 + r];
}

// ---------------------------------------------------------------------------
extern "C" void kernel_launch(void* const* d_in, const int* in_sizes, int n_in,
                              void* d_out, int out_size, void* d_ws, size_t ws_size,
                              hipStream_t stream)
{
    const float* x    = (const float*)d_in[0];
    const float* mask = (const float*)d_in[1];
    const float* Wq   = (const float*)d_in[2];
    const float* bq   = (const float*)d_in[3];
    const float* Wk   = (const float*)d_in[4];
    const float* bk   = (const float*)d_in[5];
    const float* Wv   = (const float*)d_in[6];
    const float* bv   = (const float*)d_in[7];
    const float* Wfc  = (const float*)d_in[8];
    const float* bfc  = (const float*)d_in[9];
    float* out = (float*)d_out;

    const size_t QKV_ELEMS = (size_t)BSZ * NH * NSEQ * DK;  // 1,048,576
    unsigned short* Q    = (unsigned short*)d_ws;
    unsigned short* Kb   = Q + QKV_ELEMS;
    unsigned short* Vt   = Kb + QKV_ELEMS;
    unsigned short* AO   = Vt + QKV_ELEMS;
    unsigned short* WfcB = AO + QKV_ELEMS;
    unsigned short* wb   = WfcB + DM * DM;

    k_qkv<<<256, 768, 0, stream>>>(x, Wq, bq, Wk, bk, Wv, bv, Wfc, mask,
                                   Q, Kb, Vt, WfcB, wb);
    k_attn<<<1024, 256, 0, stream>>>(Q, Kb, Vt, wb, AO);
    k_fc<<<1024, 256, 0, stream>>>(AO, WfcB, bfc, out);
}